// Round 1
// baseline (500.224 us; speedup 1.0000x reference)
//
#include <hip/hip_runtime.h>
#include <cmath>

// QuantumProjection: out = (tanh(x @ W_pre.T + b_pre)*pi -> 4-qubit circuit -> z) @ W_post.T + b_post
// B=32768, D_IN=D_OUT=2048, N_QUBITS=4, N_LAYERS=2. Pure fp32.
// Memory-bound target: 268 MB read (x) + 268 MB write (out); roofline ~85 us @ 6.3 TB/s.
//
// R1 restructure: previous kernel (543.8 us ~= 1.0 TB/s) ran the ~3K-instruction
// circuit+transcendental phase redundantly on every wave (1 wave = 1 row).
// Now each wave owns 8 rows: phase 1 (dot products) stays wave-per-row for
// coalescing; lane r keeps row r's sums; phase 2 (circuit) runs ONCE per wave
// with lane r computing row r (8x amortization + tanh hoisted); phase 3
// broadcasts z via shfl and stores coalesced with W_post loads hoisted
// out of the row loop.

namespace {

constexpr int   kB        = 32768;
constexpr int   kDin      = 2048;
constexpr int   kDout     = 2048;
constexpr int   kRows     = 8;            // rows per wave
constexpr float kPi       = 3.14159265358979323846f;
constexpr float kInvSqrt2 = 0.70710678118654752440f;

__device__ __forceinline__ float2 cmul(float2 a, float2 b) {
    return make_float2(a.x * b.x - a.y * b.y, a.x * b.y + a.y * b.x);
}

__global__ __launch_bounds__(256) void qproj_kernel(
    const float* __restrict__ x,      // (B, 2048)
    const float* __restrict__ W_pre,  // (4, 2048)
    const float* __restrict__ b_pre,  // (4,)
    const float* __restrict__ qw,     // (2, 4, 3)
    const float* __restrict__ W_post, // (2048, 4)
    const float* __restrict__ b_post, // (2048,)
    float* __restrict__ out)          // (B, 2048)
{
    const int lane    = threadIdx.x & 63;
    const int wv      = threadIdx.x >> 6;
    const int wave_id = (blockIdx.x << 2) + wv;
    const int row0    = wave_id * kRows;          // grid covers B exactly

    // ---- phase 1: per row, s_i = <x_row, W_pre_i> + b_pre_i (wave-per-row, coalesced) ----
    // Lane r keeps row r's raw sums; tanh deferred to phase 2 (once per lane).
    float my_s[4] = {0.f, 0.f, 0.f, 0.f};
#pragma unroll 1
    for (int r = 0; r < kRows; ++r) {
        const float* xrow = x + (size_t)(row0 + r) * kDin;
        float acc[4] = {0.f, 0.f, 0.f, 0.f};
#pragma unroll
        for (int it = 0; it < kDin / 256; ++it) {          // 8 iterations
            const int k = it * 256 + lane * 4;
            const float4 xv = *(const float4*)(xrow + k);
            const float4 w0 = *(const float4*)(W_pre + 0 * kDin + k);
            const float4 w1 = *(const float4*)(W_pre + 1 * kDin + k);
            const float4 w2 = *(const float4*)(W_pre + 2 * kDin + k);
            const float4 w3 = *(const float4*)(W_pre + 3 * kDin + k);
            acc[0] += xv.x * w0.x + xv.y * w0.y + xv.z * w0.z + xv.w * w0.w;
            acc[1] += xv.x * w1.x + xv.y * w1.y + xv.z * w1.z + xv.w * w1.w;
            acc[2] += xv.x * w2.x + xv.y * w2.y + xv.z * w2.z + xv.w * w2.w;
            acc[3] += xv.x * w3.x + xv.y * w3.y + xv.z * w3.z + xv.w * w3.w;
        }
        // butterfly reduction: every lane ends with the full sums
#pragma unroll
        for (int off = 32; off > 0; off >>= 1) {
#pragma unroll
            for (int i = 0; i < 4; ++i) acc[i] += __shfl_xor(acc[i], off);
        }
        if (lane == r) {
#pragma unroll
            for (int i = 0; i < 4; ++i) my_s[i] = acc[i];
        }
    }

    // ---- phase 2: 4-qubit statevector, lane r computes row (row0+r) ----
    // Lanes >= kRows compute garbage from my_s=0; results discarded by shfl below.
    float av[4];
#pragma unroll
    for (int i = 0; i < 4; ++i) av[i] = tanhf(my_s[i] + b_pre[i]) * kPi;

    float2 st[16];
#pragma unroll
    for (int i = 0; i < 16; ++i) st[i] = make_float2(0.f, 0.f);
    st[0] = make_float2(1.f, 0.f);

    // Encoding: per qubit q apply M = RZ(atan(f^2)) * RY(atan(f)) * H  (fused 2x2)
#pragma unroll
    for (int q = 0; q < 4; ++q) {
        const int bq = 1 << q;
        const float f = av[q];
        float sr, cr;  sincosf(0.5f * atanf(f),     &sr, &cr);   // RY half-angle
        float sz, cz;  sincosf(0.5f * atanf(f * f), &sz, &cz);   // RZ half-angle
        const float u = kInvSqrt2 * (cr - sr);
        const float v = kInvSqrt2 * (cr + sr);
        const float2 e  = make_float2(cz, -sz);   // exp(-i rz/2)
        const float2 ec = make_float2(cz,  sz);   // conj
#pragma unroll
        for (int idx = 0; idx < 16; ++idx) {
            if (idx & bq) continue;
            const float2 a0 = st[idx], a1 = st[idx | bq];
            // RY*H = 1/sqrt2 [[c-s, c+s],[c+s, s-c]] = [[u,v],[v,-u]]
            const float2 t0 = make_float2(u * a0.x + v * a1.x, u * a0.y + v * a1.y);
            const float2 t1 = make_float2(v * a0.x - u * a1.x, v * a0.y - u * a1.y);
            st[idx]      = cmul(e,  t0);
            st[idx | bq] = cmul(ec, t1);
        }
    }

    // Entangling layers
#pragma unroll
    for (int l = 0; l < 2; ++l) {
        // CNOT ring: control c -> target (c+1)%4 ; swap within control=1 subspace
#pragma unroll
        for (int c = 0; c < 4; ++c) {
            const int t  = (c + 1) & 3;
            const int bc = 1 << c, bt = 1 << t;
#pragma unroll
            for (int idx = 0; idx < 16; ++idx) {
                if ((idx & bc) && !(idx & bt)) {
                    const float2 tmp = st[idx];
                    st[idx]      = st[idx | bt];
                    st[idx | bt] = tmp;
                }
            }
        }
        // Rot(phi, theta, omega) per qubit
#pragma unroll
        for (int q = 0; q < 4; ++q) {
            const int bq = 1 << q;
            const float phi = qw[l * 12 + q * 3 + 0];
            const float th  = qw[l * 12 + q * 3 + 1];
            const float om  = qw[l * 12 + q * 3 + 2];
            float s2, c2;  sincosf(0.5f * th,         &s2, &c2);
            float sp, cp;  sincosf(0.5f * (phi + om), &sp, &cp);
            float sm, cm;  sincosf(0.5f * (phi - om), &sm, &cm);
            // ep = (cp,-sp); em = (cm,sm)
            const float2 m00 = make_float2( cp * c2, -sp * c2);  //  ep*c
            const float2 m01 = make_float2(-cm * s2, -sm * s2);  // -em*s
            const float2 m10 = make_float2( cm * s2, -sm * s2);  //  conj(em)*s
            const float2 m11 = make_float2( cp * c2,  sp * c2);  //  conj(ep)*c
#pragma unroll
            for (int idx = 0; idx < 16; ++idx) {
                if (idx & bq) continue;
                const float2 a0 = st[idx], a1 = st[idx | bq];
                float2 n0 = cmul(m00, a0), u01 = cmul(m01, a1);
                n0.x += u01.x; n0.y += u01.y;
                float2 n1 = cmul(m10, a0), u11 = cmul(m11, a1);
                n1.x += u11.x; n1.y += u11.y;
                st[idx]      = n0;
                st[idx | bq] = n1;
            }
        }
    }

    // Measurement: z_w = sum_idx |amp|^2 * (bit_w ? -1 : +1)
    float z[4] = {0.f, 0.f, 0.f, 0.f};
#pragma unroll
    for (int idx = 0; idx < 16; ++idx) {
        const float p = st[idx].x * st[idx].x + st[idx].y * st[idx].y;
#pragma unroll
        for (int w = 0; w < 4; ++w) z[w] += (idx & (1 << w)) ? -p : p;
    }

    // ---- broadcast: zb[r][c] = z[c] of lane r (row row0+r) ----
    float zb[kRows][4];
#pragma unroll
    for (int r = 0; r < kRows; ++r) {
#pragma unroll
        for (int c = 0; c < 4; ++c) zb[r][c] = __shfl(z[c], r);
    }

    // ---- phase 3: out[row, j] = sum_i z_i * W_post[j, i] + b_post[j] ----
    // Outer loop over column tiles so W_post/b_post loads are shared by all 8 rows.
    float* obase = out + (size_t)row0 * kDout;
#pragma unroll 1
    for (int it = 0; it < kDout / 256; ++it) {             // 8 iterations
        const int j = it * 256 + lane * 4;
        const float4 bp = *(const float4*)(b_post + j);
        const float4 wa = *(const float4*)(W_post + (size_t)(j + 0) * 4);
        const float4 wb = *(const float4*)(W_post + (size_t)(j + 1) * 4);
        const float4 wc = *(const float4*)(W_post + (size_t)(j + 2) * 4);
        const float4 wd = *(const float4*)(W_post + (size_t)(j + 3) * 4);
#pragma unroll
        for (int r = 0; r < kRows; ++r) {
            float4 o;
            o.x = zb[r][0] * wa.x + zb[r][1] * wa.y + zb[r][2] * wa.z + zb[r][3] * wa.w + bp.x;
            o.y = zb[r][0] * wb.x + zb[r][1] * wb.y + zb[r][2] * wb.z + zb[r][3] * wb.w + bp.y;
            o.z = zb[r][0] * wc.x + zb[r][1] * wc.y + zb[r][2] * wc.z + zb[r][3] * wc.w + bp.z;
            o.w = zb[r][0] * wd.x + zb[r][1] * wd.y + zb[r][2] * wd.z + zb[r][3] * wd.w + bp.w;
            *(float4*)(obase + (size_t)r * kDout + j) = o;
        }
    }
}

} // namespace

extern "C" void kernel_launch(void* const* d_in, const int* in_sizes, int n_in,
                              void* d_out, int out_size, void* d_ws, size_t ws_size,
                              hipStream_t stream) {
    const float* x      = (const float*)d_in[0];
    const float* W_pre  = (const float*)d_in[1];
    const float* b_pre  = (const float*)d_in[2];
    const float* qw     = (const float*)d_in[3];
    const float* W_post = (const float*)d_in[4];
    const float* b_post = (const float*)d_in[5];
    float* out = (float*)d_out;

    // 4 waves per block, 8 rows per wave -> 32 rows/block -> 1024 blocks
    qproj_kernel<<<dim3(kB / (4 * kRows)), dim3(256), 0, stream>>>(
        x, W_pre, b_pre, qw, W_post, b_post, out);
}